// Round 7
// baseline (981.607 us; speedup 1.0000x reference)
//
#include <hip/hip_runtime.h>
#include <stdint.h>
#include <math.h>

#define INF __builtin_inff()

typedef __attribute__((ext_vector_type(4))) float f32x4;
typedef __attribute__((ext_vector_type(8))) short s16x8;
typedef __attribute__((ext_vector_type(4))) short s16x4;
typedef __attribute__((ext_vector_type(4))) char c8x4;

#define S_XMN 0
#define S_XMX 1
#define S_T1MN 2
#define S_T1MX 3
#define S_T4MN 4
#define S_T4MX 5
#define S_T7MN 6
#define S_T7MX 7
#define S_CVMN 8
#define S_CVMX 9
#define S_BNMN 10
#define S_BNMX 11
#define S_SIMN 12
#define S_SIMX 13
#define S_T18MN 14
#define S_T18MX 15
#define S_W1 16
#define S_W2 17
#define S_DW 18
#define NSLOT 19

#define NTOT 16777216L   // 32*1024*512

__device__ __forceinline__ unsigned enc(float f) {
  unsigned u = __float_as_uint(f);
  return (u & 0x80000000u) ? ~u : (u | 0x80000000u);
}
__device__ __forceinline__ float dec(unsigned k) {
  return (k & 0x80000000u) ? __uint_as_float(k & 0x7FFFFFFFu) : __uint_as_float(~k);
}

struct FQ { float s, zp; };

__device__ __forceinline__ FQ fq_params(float mn_t, float mx_t) {
  float mn = fminf(mn_t, 0.0f), mx = fmaxf(mx_t, 0.0f);
  FQ p;
  p.s = fmaxf((mx - mn) / 255.0f, 1e-8f);
  p.zp = -128.0f - rintf(mn / p.s);
  return p;
}
__device__ __forceinline__ float fq_apply(float x, FQ p) {
  float q = rintf(x / p.s) + p.zp;
  q = fminf(fmaxf(q, -128.0f), 127.0f);
  return (q - p.zp) * p.s;
}
__device__ __forceinline__ float fq_qmz(float x, FQ p) {
  float q = rintf(x / p.s) + p.zp;
  q = fminf(fmaxf(q, -128.0f), 127.0f);
  return q - p.zp;
}
// quantize to LUT index in [0,255]  (IEEE div - matches reference rounding)
__device__ __forceinline__ int qidx(float x, FQ p) {
  float q = rintf(x / p.s) + p.zp;
  q = fminf(fmaxf(q, -128.0f), 127.0f);
  return (int)q + 128;
}
__device__ __forceinline__ int qcode(float x, FQ p) {
  float q = rintf(x / p.s) + p.zp;
  q = fminf(fmaxf(q, -128.0f), 127.0f);
  return (int)q;
}
__device__ __forceinline__ void fq_pair(const unsigned* slots, int idx, FQ& p1, FQ& p2) {
  float mn = dec(slots[idx]), mx = dec(slots[idx + 1]);
  p1 = fq_params(mn, mx);
  float ymn = fq_apply(mn, p1), ymx = fq_apply(mx, p1);
  p2 = fq_params(ymn, ymx);
}
__device__ __forceinline__ unsigned short to_bf16(float v) {
  return (unsigned short)(__float_as_uint(v) >> 16);
}

// async global->LDS, 16B per lane; LDS dest is wave-uniform base + lane*16
__device__ __forceinline__ void gload_lds16(const void* g, void* l) {
  __builtin_amdgcn_global_load_lds(
      (const __attribute__((address_space(1))) unsigned int*)g,
      (__attribute__((address_space(3))) unsigned int*)l, 16, 0, 0);
}

__device__ __forceinline__ void mm_block_atomic(float mn, float mx, unsigned* smn, unsigned* smx) {
#pragma unroll
  for (int o = 32; o > 0; o >>= 1) {
    mn = fminf(mn, __shfl_down(mn, o, 64));
    mx = fmaxf(mx, __shfl_down(mx, o, 64));
  }
  __shared__ float rmn[16], rmx[16];
  int lane = threadIdx.x & 63, wid = threadIdx.x >> 6;
  int nw = blockDim.x >> 6;
  __syncthreads();
  if (lane == 0) { rmn[wid] = mn; rmx[wid] = mx; }
  __syncthreads();
  if (threadIdx.x == 0) {
    for (int i = 1; i < nw; ++i) { mn = fminf(mn, rmn[i]); mx = fmaxf(mx, rmx[i]); }
    atomicMin(smn, enc(mn));
    atomicMax(smx, enc(mx));
  }
}

__device__ __forceinline__ float wave_sum(float v) {
#pragma unroll
  for (int o = 1; o < 64; o <<= 1) v += __shfl_xor(v, o, 64);
  return v;
}

__global__ void k_init(unsigned* __restrict__ slots, const float* __restrict__ gm,
                       const float* __restrict__ vr, float* __restrict__ gs) {
  int i = threadIdx.x;
  if (i < NSLOT) slots[i] = (i < 16) ? ((i & 1) ? enc(-INF) : enc(INF)) : enc(0.0f);
  gs[i] = gm[i] / sqrtf(vr[i] + 1e-5f);
}

__global__ __launch_bounds__(256) void k_redmm(const float* __restrict__ x, unsigned* __restrict__ slots) {
  long i = ((long)blockIdx.x * 256 + threadIdx.x) * 4;
  const long stride = (long)2048 * 256 * 4;
  float mn = INF, mx = -INF;
  for (; i < NTOT; i += stride) {
    f32x4 v = *(const f32x4*)(x + i);
    mn = fminf(mn, fminf(fminf(v.x, v.y), fminf(v.z, v.w)));
    mx = fmaxf(mx, fmaxf(fmaxf(v.x, v.y), fmaxf(v.z, v.w)));
  }
  mm_block_atomic(mn, mx, slots + S_XMN, slots + S_XMX);
}

__global__ __launch_bounds__(256) void k_wabs(const float* __restrict__ w1, const float* __restrict__ w2,
                                              const float* __restrict__ dw, unsigned* __restrict__ slots) {
  int b = blockIdx.x;
  const float* p; int slot; long base;
  if (b < 2048) { p = w1; slot = S_W1; base = (long)b * 256; }
  else if (b < 3072) { p = w2; slot = S_W2; base = (long)(b - 2048) * 256; }
  else { p = dw; slot = S_DW; base = (long)(b - 3072) * 256; }
  float v = fabsf(p[base + threadIdx.x]);
#pragma unroll
  for (int o = 32; o > 0; o >>= 1) v = fmaxf(v, __shfl_down(v, o, 64));
  __shared__ float r[4];
  int lane = threadIdx.x & 63, wid = threadIdx.x >> 6;
  if (lane == 0) r[wid] = v;
  __syncthreads();
  if (threadIdx.x == 0) {
    v = fmaxf(fmaxf(r[0], r[1]), fmaxf(r[2], r[3]));
    atomicMax(slots + slot, enc(v));
  }
}

// weight quant; dw written TRANSPOSED: dwqT[k*512 + f]
__global__ __launch_bounds__(256) void k_wq(const float* __restrict__ w1, const float* __restrict__ w2,
    const float* __restrict__ dw, unsigned short* __restrict__ w1q, unsigned short* __restrict__ w2q,
    float* __restrict__ dwqT, const unsigned* __restrict__ slots) {
  int b = blockIdx.x;
  if (b < 2048) {
    float s = fmaxf(dec(slots[S_W1]) / 127.0f, 1e-8f);
    long i = (long)b * 256 + threadIdx.x;
    float q = fminf(fmaxf(rintf(w1[i] / s), -128.0f), 127.0f);
    w1q[i] = to_bf16(q);
  } else if (b < 3072) {
    float s = fmaxf(dec(slots[S_W2]) / 127.0f, 1e-8f);
    long i = (long)(b - 2048) * 256 + threadIdx.x;
    float q = fminf(fmaxf(rintf(w2[i] / s), -128.0f), 127.0f);
    w2q[i] = to_bf16(q);
  } else {
    float s = fmaxf(dec(slots[S_DW]) / 127.0f, 1e-8f);
    int i = (b - 3072) * 256 + threadIdx.x;   // i < 15872 = 512*31
    int f = i / 31, k = i % 31;
    float q = fminf(fmaxf(rintf(dw[i] / s), -128.0f), 127.0f);
    dwqT[k * 512 + f] = q;
  }
}

// LN core on decoded fq0 values; MUST be identical arithmetic in both LN passes.
__device__ __forceinline__ void ln_core(float* a, const f32x4& sc0, const f32x4& sc1,
                                        const f32x4& bi0, const f32x4& bi1) {
  float s = a[0] + a[1] + a[2] + a[3] + a[4] + a[5] + a[6] + a[7];
  float mean = wave_sum(s) / 512.0f;
#pragma unroll
  for (int j = 0; j < 8; ++j) a[j] -= mean;
  float l1 = fabsf(a[0]) + fabsf(a[1]) + fabsf(a[2]) + fabsf(a[3])
           + fabsf(a[4]) + fabsf(a[5]) + fabsf(a[6]) + fabsf(a[7]);
  float denom = wave_sum(l1) / 512.0f + 1e-5f;
#pragma unroll
  for (int j = 0; j < 4; ++j) {
    a[j]     = fmaf(a[j] / denom,     sc0[j], bi0[j]);
    a[4 + j] = fmaf(a[4 + j] / denom, sc1[j], bi1[j]);
  }
}

// pass 1: quantize x -> int8 codes (cache), LN min/max (no t1 store)
__global__ __launch_bounds__(256) void k_lnmm(const float* __restrict__ x, const float* __restrict__ lns,
    const float* __restrict__ lnb, signed char* __restrict__ qx, unsigned* __restrict__ slots) {
  FQ p0 = fq_params(dec(slots[S_XMN]), dec(slots[S_XMX]));
  int lane = threadIdx.x & 63, wv = threadIdx.x >> 6;
  long gw = (long)blockIdx.x * 4 + wv;
  f32x4 sc0 = *(const f32x4*)(lns + lane * 4);
  f32x4 sc1 = *(const f32x4*)(lns + 256 + lane * 4);
  f32x4 bi0 = *(const f32x4*)(lnb + lane * 4);
  f32x4 bi1 = *(const f32x4*)(lnb + 256 + lane * 4);
  float lmn = INF, lmx = -INF;
  for (int r = 0; r < 4; ++r) {
    long row = gw + (long)r * 8192;
    f32x4 v0 = *(const f32x4*)(x + row * 512 + lane * 4);
    f32x4 v1 = *(const f32x4*)(x + row * 512 + 256 + lane * 4);
    float a[8];
    c8x4 c0, c1;
#pragma unroll
    for (int j = 0; j < 4; ++j) {
      int q0 = qcode(v0[j], p0), q1 = qcode(v1[j], p0);
      c0[j] = (signed char)q0; c1[j] = (signed char)q1;
      a[j]     = ((float)q0 - p0.zp) * p0.s;
      a[4 + j] = ((float)q1 - p0.zp) * p0.s;
    }
    *(c8x4*)(qx + row * 512 + lane * 4) = c0;
    *(c8x4*)(qx + row * 512 + 256 + lane * 4) = c1;
    ln_core(a, sc0, sc1, bi0, bi1);
#pragma unroll
    for (int j = 0; j < 8; ++j) { lmn = fminf(lmn, a[j]); lmx = fmaxf(lmx, a[j]); }
  }
  mm_block_atomic(lmn, lmx, slots + S_T1MN, slots + S_T1MX);
}

// pass 2: recompute LN from codes (bitwise-identical), double-fq via LUT -> bf16 int A1
__global__ __launch_bounds__(256) void k_qa(const signed char* __restrict__ qx, const float* __restrict__ lns,
    const float* __restrict__ lnb, unsigned short* __restrict__ A1, const unsigned* __restrict__ slots) {
  __shared__ unsigned short lut[256];
  FQ p0 = fq_params(dec(slots[S_XMN]), dec(slots[S_XMX]));
  FQ p1, p2; fq_pair(slots, S_T1MN, p1, p2);
  {
    int i = threadIdx.x;
    float y1 = ((float)(i - 128) - p1.zp) * p1.s;
    lut[i] = to_bf16(fq_qmz(y1, p2));
  }
  __syncthreads();
  int lane = threadIdx.x & 63, wv = threadIdx.x >> 6;
  long gw = (long)blockIdx.x * 4 + wv;
  f32x4 sc0 = *(const f32x4*)(lns + lane * 4);
  f32x4 sc1 = *(const f32x4*)(lns + 256 + lane * 4);
  f32x4 bi0 = *(const f32x4*)(lnb + lane * 4);
  f32x4 bi1 = *(const f32x4*)(lnb + 256 + lane * 4);
  for (int r = 0; r < 4; ++r) {
    long row = gw + (long)r * 8192;
    c8x4 c0 = *(const c8x4*)(qx + row * 512 + lane * 4);
    c8x4 c1 = *(const c8x4*)(qx + row * 512 + 256 + lane * 4);
    float a[8];
#pragma unroll
    for (int j = 0; j < 4; ++j) {
      a[j]     = ((float)(int)c0[j] - p0.zp) * p0.s;
      a[4 + j] = ((float)(int)c1[j] - p0.zp) * p0.s;
    }
    ln_core(a, sc0, sc1, bi0, bi1);
    s16x4 q0, q1;
#pragma unroll
    for (int j = 0; j < 4; ++j) {
      q0[j] = (short)lut[qidx(a[j], p1)];
      q1[j] = (short)lut[qidx(a[4 + j], p1)];
    }
    *(s16x4*)(A1 + row * 512 + lane * 4) = q0;
    *(s16x4*)(A1 + row * 512 + 256 + lane * 4) = q1;
  }
}

// bf16-integer MFMA GEMM; XCD-chunked remap; global_load_lds staging with
// pre-swizzled SOURCE column (LDS dest linear).
__global__ __launch_bounds__(256) void k_gemm(const unsigned short* __restrict__ A,
    const unsigned short* __restrict__ Bm, const float* __restrict__ bias,
    float* __restrict__ C, int N, unsigned* __restrict__ slots, int mmIdx, int wIdx, int omIdx) {
  __shared__ __align__(16) unsigned short lA[128 * 64];
  __shared__ __align__(16) unsigned short lB[128 * 64];
  FQ p1, p2; fq_pair(slots, mmIdx, p1, p2);
  float sw = fmaxf(dec(slots[wIdx]) / 127.0f, 1e-8f);
  float sAB = p2.s * sw;
  int tid = threadIdx.x;
  int nbx = gridDim.x;
  int total = nbx * gridDim.y;
  int id = blockIdx.y * nbx + blockIdx.x;
  int chunk = total >> 3;
  int d = (id & 7) * chunk + (id >> 3);
  int m0 = (d / nbx) * 128, n0 = (d % nbx) * 128;
  int lane = tid & 63, w = tid >> 6;
  int wm = (w >> 1) * 64, wn = (w & 1) * 64;
  const f32x4 fz = {0.0f, 0.0f, 0.0f, 0.0f};
  f32x4 acc[4][4];
#pragma unroll
  for (int mi = 0; mi < 4; ++mi)
#pragma unroll
    for (int ni = 0; ni < 4; ++ni) acc[mi][ni] = fz;
  // staging geometry: per wave w, call i covers rows w*32+i*8 .. +8, 16B/lane
  int r8 = lane >> 3;                 // row within 8-row group
  int c8 = (lane & 7) * 8;            // u16 col of this lane's 16B chunk
  int srcc = c8 ^ (r8 * 8);           // pre-swizzled source column
  const unsigned short* Abase[4];
  const unsigned short* Bbase[4];
#pragma unroll
  for (int i = 0; i < 4; ++i) {
    int row = w * 32 + i * 8 + r8;
    Abase[i] = A + (long)(m0 + row) * 512 + srcc;
    Bbase[i] = Bm + (long)(n0 + row) * 512 + srcc;
  }
  char* lAc = (char*)lA;
  char* lBc = (char*)lB;
  int fr = lane & 15;
  int fc = (lane >> 4) * 8;
  for (int kt = 0; kt < 8; ++kt) {
    if (kt) __syncthreads();          // previous compute done before overwrite
#pragma unroll
    for (int i = 0; i < 4; ++i) {
      gload_lds16(Abase[i] + kt * 64, lAc + (w * 4 + i) * 1024);
      gload_lds16(Bbase[i] + kt * 64, lBc + (w * 4 + i) * 1024);
    }
    __syncthreads();                  // drains vmcnt -> LDS tile ready
#pragma unroll
    for (int ks = 0; ks < 2; ++ks) {
      s16x8 af[4], bfv[4];
#pragma unroll
      for (int mi = 0; mi < 4; ++mi) {
        int r = wm + mi * 16 + fr;
        af[mi] = *(const s16x8*)&lA[r * 64 + ((ks * 32 + fc) ^ ((r & 7) * 8))];
      }
#pragma unroll
      for (int ni = 0; ni < 4; ++ni) {
        int r = wn + ni * 16 + fr;
        bfv[ni] = *(const s16x8*)&lB[r * 64 + ((ks * 32 + fc) ^ ((r & 7) * 8))];
      }
#pragma unroll
      for (int mi = 0; mi < 4; ++mi)
#pragma unroll
        for (int ni = 0; ni < 4; ++ni)
          acc[mi][ni] = __builtin_amdgcn_mfma_f32_16x16x32_bf16(af[mi], bfv[ni], acc[mi][ni], 0, 0, 0);
    }
  }
  float lmn = INF, lmx = -INF;
  int rb0 = m0 + wm + ((lane >> 4) << 2);
  int cb0 = n0 + wn + (lane & 15);
#pragma unroll
  for (int mi = 0; mi < 4; ++mi) {
#pragma unroll
    for (int ni = 0; ni < 4; ++ni) {
      int col = cb0 + ni * 16;
      float bv = bias[col];
#pragma unroll
      for (int r = 0; r < 4; ++r) {
        int rowi = rb0 + mi * 16 + r;
        float v = sAB * acc[mi][ni][r] + bv;
        C[(long)rowi * N + col] = v;
        lmn = fminf(lmn, v); lmx = fmaxf(lmx, v);
      }
    }
  }
  mm_block_atomic(lmn, lmx, slots + omIdx, slots + omIdx + 1);
}

// GLU: read t4, emit packed (qa,qg); mm(t7) via LUT product (no expf in loop)
__global__ __launch_bounds__(256) void k_glu(const float* __restrict__ t4, unsigned short* __restrict__ pair,
                                             unsigned* __restrict__ slots) {
  __shared__ float lutf[256];
  __shared__ float sglut[256];
  FQ p1, p2; fq_pair(slots, S_T4MN, p1, p2);
  {
    int i = threadIdx.x;
    float y2 = fq_apply(((float)(i - 128) - p1.zp) * p1.s, p2);
    lutf[i] = y2;
    sglut[i] = 1.0f / (1.0f + expf(-y2));
  }
  __syncthreads();
  long i = ((long)blockIdx.x * 256 + threadIdx.x) * 4;
  const long stride = (long)2048 * 256 * 4;
  float lmn = INF, lmx = -INF;
  for (; i < NTOT; i += stride) {
    long r = i >> 9;
    int c = (int)(i & 511);
    const float* pa = t4 + r * 1024 + c;
    f32x4 av = *(const f32x4*)pa;
    f32x4 gv = *(const f32x4*)(pa + 512);
    s16x4 o;
#pragma unroll
    for (int j = 0; j < 4; ++j) {
      int qa = qidx(av[j], p1);
      int qg = qidx(gv[j], p1);
      o[j] = (short)(unsigned short)(qa | (qg << 8));
      float y = lutf[qa] * sglut[qg];
      lmn = fminf(lmn, y); lmx = fmaxf(lmx, y);
    }
    *(s16x4*)(pair + i) = o;
  }
  mm_block_atomic(lmn, lmx, slots + S_T7MN, slots + S_T7MX);
}

// decode pair -> t7 value (identical product) -> double-fq composed int8 code q7
__global__ __launch_bounds__(256) void k_qt7(const unsigned short* __restrict__ pair,
                                             signed char* __restrict__ q7,
                                             const unsigned* __restrict__ slots) {
  __shared__ float lutf[256];
  __shared__ float sglut[256];
  __shared__ signed char lutq[256];
  FQ g1, g2; fq_pair(slots, S_T4MN, g1, g2);
  FQ p1, p2; fq_pair(slots, S_T7MN, p1, p2);
  {
    int i = threadIdx.x;
    float y2 = fq_apply(((float)(i - 128) - g1.zp) * g1.s, g2);
    lutf[i] = y2;
    sglut[i] = 1.0f / (1.0f + expf(-y2));
    float y1 = ((float)(i - 128) - p1.zp) * p1.s;
    float q = fminf(fmaxf(rintf(y1 / p2.s) + p2.zp, -128.0f), 127.0f);
    lutq[i] = (signed char)(int)q;
  }
  __syncthreads();
  long i = ((long)blockIdx.x * 256 + threadIdx.x) * 4;
  const long stride = (long)2048 * 256 * 4;
  for (; i < NTOT; i += stride) {
    s16x4 pv = *(const s16x4*)(pair + i);
    c8x4 o;
#pragma unroll
    for (int j = 0; j < 4; ++j) {
      unsigned u = (unsigned short)pv[j];
      float y = lutf[u & 255] * sglut[u >> 8];
      o[j] = lutq[qidx(y, p1)];
    }
    *(c8x4*)(q7 + i) = o;
  }
}

// depthwise conv: t-tile=8 per thread; constant-trip loops, all guards compile-time.
// o[8] + wv[31] stay in registers (no scratch). Exact integer sums; identical
// tap order across both passes (same template).
// STORE=0: conv min/max only. STORE=1: quantize->qcv + bn min/max.
template<int STORE>
__global__ __launch_bounds__(256) void k_conv(const signed char* __restrict__ q7,
    const float* __restrict__ dwqT, const float* __restrict__ dwb,
    signed char* __restrict__ qcv, const float* __restrict__ gs, const float* __restrict__ mu,
    const float* __restrict__ bt, unsigned* __restrict__ slots) {
  __shared__ signed char lutq[256];
  FQ p1, p2; fq_pair(slots, S_T7MN, p1, p2);
  float sdw = fmaxf(dec(slots[S_DW]) / 127.0f, 1e-8f);
  float scv = p2.s * sdw;
  float zp2 = p2.zp;
  FQ c1, c2;
  if (STORE) {
    fq_pair(slots, S_CVMN, c1, c2);
    int i = threadIdx.x;
    float y1 = ((float)(i - 128) - c1.zp) * c1.s;
    float q = fminf(fmaxf(rintf(y1 / c2.s) + c2.zp, -128.0f), 127.0f);
    lutq[i] = (signed char)(int)q;
    __syncthreads();
  }
  int t0 = blockIdx.x * 8;            // 128 t-tiles
  int f = blockIdx.y * 256 + threadIdx.x;
  int b = blockIdx.z;
  const signed char* base = q7 + (long)b * 1024 * 512 + f;
  float wv[31];
#pragma unroll
  for (int k = 0; k < 31; ++k) wv[k] = dwqT[k * 512 + f];
  float o[8];
#pragma unroll
  for (int j = 0; j < 8; ++j) o[j] = 0.0f;
#pragma unroll
  for (int r = 0; r < 38; ++r) {      // constant trip; fully unrolls
    int t = t0 - 15 + r;
    float q = 0.0f;
    if ((unsigned)t < 1024u) q = (float)(int)base[(long)t * 512] - zp2;
#pragma unroll
    for (int j = 0; j < 8; ++j) {     // constant trip; guards fold per (r,j)
      if (j <= r && r - j <= 30)
        o[j] += q * wv[r - j];        // exact integers; k ascending per j
    }
  }
  float bias = dwb[f];
  float gsv = 0.f, muv = 0.f, btv = 0.f;
  if (STORE) { gsv = gs[f]; muv = mu[f]; btv = bt[f]; }
  signed char* orow = STORE ? (qcv + ((long)b * 1024 + t0) * 512 + f) : nullptr;
  float lmn = INF, lmx = -INF;
#pragma unroll
  for (int j = 0; j < 8; ++j) {
    float v = fmaf(scv, o[j], bias);
    if (STORE) {
      signed char qc = lutq[qidx(v, c1)];
      orow[(long)j * 512] = qc;
      float y2 = ((float)(int)qc - c2.zp) * c2.s;
      float z = fmaf(y2 - muv, gsv, btv);
      lmn = fminf(lmn, z); lmx = fmaxf(lmx, z);
    } else {
      lmn = fminf(lmn, v); lmx = fmaxf(lmx, v);
    }
  }
  if (STORE) mm_block_atomic(lmn, lmx, slots + S_BNMN, slots + S_BNMX);
  else       mm_block_atomic(lmn, lmx, slots + S_CVMN, slots + S_CVMX);
}

// silu min/max: qcv codes -> bn -> fq2-index -> sillut (no expf in loop)
__global__ __launch_bounds__(256) void k_silumm(const signed char* __restrict__ qcv,
    const float* __restrict__ gs, const float* __restrict__ mu, const float* __restrict__ bt,
    unsigned* __restrict__ slots) {
  __shared__ float sillut[256];
  FQ c1, c2; fq_pair(slots, S_CVMN, c1, c2);
  FQ b1q, b2q; fq_pair(slots, S_BNMN, b1q, b2q);
  {
    int i = threadIdx.x;
    float z2 = fq_apply(((float)(i - 128) - b1q.zp) * b1q.s, b2q);
    sillut[i] = z2 * (1.0f / (1.0f + expf(-z2)));
  }
  __syncthreads();
  float s2 = c2.s, zp2 = c2.zp;
  long i = ((long)blockIdx.x * 256 + threadIdx.x) * 4;
  const long stride = (long)2048 * 256 * 4;
  float lmn = INF, lmx = -INF;
  for (; i < NTOT; i += stride) {
    int f0 = (int)(i & 511);
    c8x4 qv = *(const c8x4*)(qcv + i);
    f32x4 g4 = *(const f32x4*)(gs + f0);
    f32x4 m4 = *(const f32x4*)(mu + f0);
    f32x4 b4 = *(const f32x4*)(bt + f0);
#pragma unroll
    for (int j = 0; j < 4; ++j) {
      float y2 = ((float)(int)qv[j] - zp2) * s2;
      float z = fmaf(y2 - m4[j], g4[j], b4[j]);
      float si = sillut[qidx(z, b1q)];
      lmn = fminf(lmn, si); lmx = fmaxf(lmx, si);
    }
  }
  mm_block_atomic(lmn, lmx, slots + S_SIMN, slots + S_SIMX);
}

// A2 build: qcv code -> bn -> composed LUT (fq2 -> silu -> double-fq -> bf16 int)
__global__ __launch_bounds__(256) void k_q2(const signed char* __restrict__ qcv,
    const float* __restrict__ gs, const float* __restrict__ mu, const float* __restrict__ bt,
    unsigned short* __restrict__ A2, const unsigned* __restrict__ slots) {
  __shared__ unsigned short lutc[256];
  FQ c1, c2; fq_pair(slots, S_CVMN, c1, c2);
  FQ b1q, b2q; fq_pair(slots, S_BNMN, b1q, b2q);
  FQ s1q, s2q; fq_pair(slots, S_SIMN, s1q, s2q);
  {
    int i = threadIdx.x;
    float z2 = fq_apply(((float)(i - 128) - b1q.zp) * b1q.s, b2q);
    float si = z2 * (1.0f / (1.0f + expf(-z2)));
    float ys = ((float)(qidx(si, s1q) - 128) - s1q.zp) * s1q.s;
    lutc[i] = to_bf16(fq_qmz(ys, s2q));
  }
  __syncthreads();
  float s2 = c2.s, zp2 = c2.zp;
  long i = ((long)blockIdx.x * 256 + threadIdx.x) * 4;
  const long stride = (long)2048 * 256 * 4;
  for (; i < NTOT; i += stride) {
    int f0 = (int)(i & 511);
    c8x4 qv = *(const c8x4*)(qcv + i);
    f32x4 g4 = *(const f32x4*)(gs + f0);
    f32x4 m4 = *(const f32x4*)(mu + f0);
    f32x4 b4 = *(const f32x4*)(bt + f0);
    s16x4 o;
#pragma unroll
    for (int j = 0; j < 4; ++j) {
      float y2 = ((float)(int)qv[j] - zp2) * s2;
      float z = fmaf(y2 - m4[j], g4[j], b4[j]);
      o[j] = (short)lutc[qidx(z, b1q)];
    }
    *(s16x4*)(A2 + i) = o;
  }
}

__global__ __launch_bounds__(256) void k_final(const float* __restrict__ t18, float* __restrict__ out,
                                               const unsigned* __restrict__ slots) {
  FQ p = fq_params(dec(slots[S_T18MN]), dec(slots[S_T18MX]));
  long i = ((long)blockIdx.x * 256 + threadIdx.x) * 4;
  const long stride = (long)2048 * 256 * 4;
  for (; i < NTOT; i += stride) {
    f32x4 v = *(const f32x4*)(t18 + i);
    f32x4 o;
#pragma unroll
    for (int j = 0; j < 4; ++j) o[j] = fq_apply(v[j], p);
    *(f32x4*)(out + i) = o;
  }
}

extern "C" void kernel_launch(void* const* d_in, const int* in_sizes, int n_in,
                              void* d_out, int out_size, void* d_ws, size_t ws_size,
                              hipStream_t stream) {
  const float* x   = (const float*)d_in[0];
  const float* lns = (const float*)d_in[1];
  const float* lnb = (const float*)d_in[2];
  const float* w1  = (const float*)d_in[3];
  const float* b1  = (const float*)d_in[4];
  const float* dw  = (const float*)d_in[5];
  const float* dwb = (const float*)d_in[6];
  const float* gm  = (const float*)d_in[7];
  const float* bt  = (const float*)d_in[8];
  const float* mu  = (const float*)d_in[9];
  const float* vr  = (const float*)d_in[10];
  const float* w2  = (const float*)d_in[11];
  const float* b2  = (const float*)d_in[12];
  float* out = (float*)d_out;
  char* ws = (char*)d_ws;

  // workspace (aliased lifetimes):
  //  [0,134M):        t4; after t4 dead: qcv [0,16.7M), A2 [16.7M,50.3M), t18 [50.3M,117.4M)
  //  [134M,167.8M):   A1 (bf16) -> pair (u16)
  //  [167.8M,184.5M): qx (int8) -> q7 (int8)
  //  [184.5M...):     w1q(1MB), w2q(0.5MB), dwqT(63.5KB), gs(2KB), slots
  const size_t O_A2  = 16777216;
  const size_t O_T18 = 50331648;
  const size_t O_A1  = 134217728;
  const size_t O_QX  = 167772160;
  const size_t O_WQ  = 184549376;
  const size_t NEED = O_WQ + 1048576 + 524288 + 63488 + 2048 + 256;
  if (ws_size < NEED) return;

  float* t4   = (float*)ws;
  signed char* qcv = (signed char*)ws;
  unsigned short* A2 = (unsigned short*)(ws + O_A2);
  float* t18  = (float*)(ws + O_T18);
  unsigned short* A1 = (unsigned short*)(ws + O_A1);
  unsigned short* pair = (unsigned short*)(ws + O_A1);
  signed char* qx = (signed char*)(ws + O_QX);
  signed char* q7 = (signed char*)(ws + O_QX);
  unsigned short* w1q = (unsigned short*)(ws + O_WQ);
  unsigned short* w2q = (unsigned short*)(ws + O_WQ + 1048576);
  float* dwqT = (float*)(ws + O_WQ + 1048576 + 524288);
  float* gs  = (float*)(ws + O_WQ + 1048576 + 524288 + 63488);
  unsigned* slots = (unsigned*)(ws + O_WQ + 1048576 + 524288 + 63488 + 2048);

  k_init<<<1, 512, 0, stream>>>(slots, gm, vr, gs);
  k_wabs<<<3134, 256, 0, stream>>>(w1, w2, dw, slots);
  k_wq<<<3134, 256, 0, stream>>>(w1, w2, dw, w1q, w2q, dwqT, slots);
  k_redmm<<<2048, 256, 0, stream>>>(x, slots);
  k_lnmm<<<2048, 256, 0, stream>>>(x, lns, lnb, qx, slots);
  k_qa<<<2048, 256, 0, stream>>>(qx, lns, lnb, A1, slots);
  k_gemm<<<dim3(8, 256), 256, 0, stream>>>(A1, w1q, b1, t4, 1024, slots, S_T1MN, S_W1, S_T4MN);
  k_glu<<<2048, 256, 0, stream>>>(t4, pair, slots);
  k_qt7<<<2048, 256, 0, stream>>>(pair, q7, slots);
  k_conv<0><<<dim3(128, 2, 32), 256, 0, stream>>>(q7, dwqT, dwb, nullptr, gs, mu, bt, slots);
  k_conv<1><<<dim3(128, 2, 32), 256, 0, stream>>>(q7, dwqT, dwb, qcv, gs, mu, bt, slots);
  k_silumm<<<2048, 256, 0, stream>>>(qcv, gs, mu, bt, slots);
  k_q2<<<2048, 256, 0, stream>>>(qcv, gs, mu, bt, A2, slots);
  k_gemm<<<dim3(4, 256), 256, 0, stream>>>(A2, w2q, b2, t18, 512, slots, S_SIMN, S_W2, S_T18MN);
  k_final<<<2048, 256, 0, stream>>>(t18, out, slots);
}

// Round 9
// 950.319 us; speedup vs baseline: 1.0329x; 1.0329x over previous
//
#include <hip/hip_runtime.h>
#include <stdint.h>
#include <math.h>

#define INF __builtin_inff()

typedef __attribute__((ext_vector_type(4))) float f32x4;
typedef __attribute__((ext_vector_type(8))) short s16x8;
typedef __attribute__((ext_vector_type(4))) short s16x4;
typedef __attribute__((ext_vector_type(4))) char c8x4;
typedef __attribute__((ext_vector_type(4))) int i32x4;

#define S_XMN 0
#define S_XMX 1
#define S_T1MN 2
#define S_T1MX 3
#define S_T4MN 4
#define S_T4MX 5
#define S_T7MN 6
#define S_T7MX 7
#define S_CVMN 8
#define S_CVMX 9
#define S_BNMN 10
#define S_BNMX 11
#define S_SIMN 12
#define S_SIMX 13
#define S_T18MN 14
#define S_T18MX 15
#define S_W1 16
#define S_W2 17
#define S_DW 18
#define NSLOT 19

#define NTOT 16777216L   // 32*1024*512

__device__ __forceinline__ unsigned enc(float f) {
  unsigned u = __float_as_uint(f);
  return (u & 0x80000000u) ? ~u : (u | 0x80000000u);
}
__device__ __forceinline__ float dec(unsigned k) {
  return (k & 0x80000000u) ? __uint_as_float(k & 0x7FFFFFFFu) : __uint_as_float(~k);
}

struct FQ { float s, zp; };

__device__ __forceinline__ FQ fq_params(float mn_t, float mx_t) {
  float mn = fminf(mn_t, 0.0f), mx = fmaxf(mx_t, 0.0f);
  FQ p;
  p.s = fmaxf((mx - mn) / 255.0f, 1e-8f);
  p.zp = -128.0f - rintf(mn / p.s);
  return p;
}
__device__ __forceinline__ float fq_apply(float x, FQ p) {
  float q = rintf(x / p.s) + p.zp;
  q = fminf(fmaxf(q, -128.0f), 127.0f);
  return (q - p.zp) * p.s;
}
__device__ __forceinline__ float fq_qmz(float x, FQ p) {
  float q = rintf(x / p.s) + p.zp;
  q = fminf(fmaxf(q, -128.0f), 127.0f);
  return q - p.zp;
}
// quantize to LUT index in [0,255]  (IEEE div - matches reference rounding)
__device__ __forceinline__ int qidx(float x, FQ p) {
  float q = rintf(x / p.s) + p.zp;
  q = fminf(fmaxf(q, -128.0f), 127.0f);
  return (int)q + 128;
}
__device__ __forceinline__ int qcode(float x, FQ p) {
  float q = rintf(x / p.s) + p.zp;
  q = fminf(fmaxf(q, -128.0f), 127.0f);
  return (int)q;
}
__device__ __forceinline__ void fq_pair(const unsigned* slots, int idx, FQ& p1, FQ& p2) {
  float mn = dec(slots[idx]), mx = dec(slots[idx + 1]);
  p1 = fq_params(mn, mx);
  float ymn = fq_apply(mn, p1), ymx = fq_apply(mx, p1);
  p2 = fq_params(ymn, ymx);
}
__device__ __forceinline__ unsigned short to_bf16(float v) {
  return (unsigned short)(__float_as_uint(v) >> 16);
}

// async global->LDS, 16B per lane; LDS dest is wave-uniform base + lane*16
__device__ __forceinline__ void gload_lds16(const void* g, void* l) {
  __builtin_amdgcn_global_load_lds(
      (const __attribute__((address_space(1))) unsigned int*)g,
      (__attribute__((address_space(3))) unsigned int*)l, 16, 0, 0);
}

__device__ __forceinline__ void mm_block_atomic(float mn, float mx, unsigned* smn, unsigned* smx) {
#pragma unroll
  for (int o = 32; o > 0; o >>= 1) {
    mn = fminf(mn, __shfl_down(mn, o, 64));
    mx = fmaxf(mx, __shfl_down(mx, o, 64));
  }
  __shared__ float rmn[16], rmx[16];
  int lane = threadIdx.x & 63, wid = threadIdx.x >> 6;
  int nw = blockDim.x >> 6;
  __syncthreads();
  if (lane == 0) { rmn[wid] = mn; rmx[wid] = mx; }
  __syncthreads();
  if (threadIdx.x == 0) {
    for (int i = 1; i < nw; ++i) { mn = fminf(mn, rmn[i]); mx = fmaxf(mx, rmx[i]); }
    atomicMin(smn, enc(mn));
    atomicMax(smx, enc(mx));
  }
}

__device__ __forceinline__ float wave_sum(float v) {
#pragma unroll
  for (int o = 1; o < 64; o <<= 1) v += __shfl_xor(v, o, 64);
  return v;
}

__global__ void k_init(unsigned* __restrict__ slots, const float* __restrict__ gm,
                       const float* __restrict__ vr, float* __restrict__ gs) {
  int i = threadIdx.x;
  if (i < NSLOT) slots[i] = (i < 16) ? ((i & 1) ? enc(-INF) : enc(INF)) : enc(0.0f);
  gs[i] = gm[i] / sqrtf(vr[i] + 1e-5f);
}

__global__ __launch_bounds__(256) void k_redmm(const float* __restrict__ x, unsigned* __restrict__ slots) {
  long i = ((long)blockIdx.x * 256 + threadIdx.x) * 4;
  const long stride = (long)2048 * 256 * 4;
  float mn = INF, mx = -INF;
  for (; i < NTOT; i += stride) {
    f32x4 v = *(const f32x4*)(x + i);
    mn = fminf(mn, fminf(fminf(v.x, v.y), fminf(v.z, v.w)));
    mx = fmaxf(mx, fmaxf(fmaxf(v.x, v.y), fmaxf(v.z, v.w)));
  }
  mm_block_atomic(mn, mx, slots + S_XMN, slots + S_XMX);
}

__global__ __launch_bounds__(256) void k_wabs(const float* __restrict__ w1, const float* __restrict__ w2,
                                              const float* __restrict__ dw, unsigned* __restrict__ slots) {
  int b = blockIdx.x;
  const float* p; int slot; long base;
  if (b < 2048) { p = w1; slot = S_W1; base = (long)b * 256; }
  else if (b < 3072) { p = w2; slot = S_W2; base = (long)(b - 2048) * 256; }
  else { p = dw; slot = S_DW; base = (long)(b - 3072) * 256; }
  float v = fabsf(p[base + threadIdx.x]);
#pragma unroll
  for (int o = 32; o > 0; o >>= 1) v = fmaxf(v, __shfl_down(v, o, 64));
  __shared__ float r[4];
  int lane = threadIdx.x & 63, wid = threadIdx.x >> 6;
  if (lane == 0) r[wid] = v;
  __syncthreads();
  if (threadIdx.x == 0) {
    v = fmaxf(fmaxf(r[0], r[1]), fmaxf(r[2], r[3]));
    atomicMax(slots + slot, enc(v));
  }
}

// weight quant; dw written TRANSPOSED: dwqT[k*512 + f]
__global__ __launch_bounds__(256) void k_wq(const float* __restrict__ w1, const float* __restrict__ w2,
    const float* __restrict__ dw, unsigned short* __restrict__ w1q, unsigned short* __restrict__ w2q,
    float* __restrict__ dwqT, const unsigned* __restrict__ slots) {
  int b = blockIdx.x;
  if (b < 2048) {
    float s = fmaxf(dec(slots[S_W1]) / 127.0f, 1e-8f);
    long i = (long)b * 256 + threadIdx.x;
    float q = fminf(fmaxf(rintf(w1[i] / s), -128.0f), 127.0f);
    w1q[i] = to_bf16(q);
  } else if (b < 3072) {
    float s = fmaxf(dec(slots[S_W2]) / 127.0f, 1e-8f);
    long i = (long)(b - 2048) * 256 + threadIdx.x;
    float q = fminf(fmaxf(rintf(w2[i] / s), -128.0f), 127.0f);
    w2q[i] = to_bf16(q);
  } else {
    float s = fmaxf(dec(slots[S_DW]) / 127.0f, 1e-8f);
    int i = (b - 3072) * 256 + threadIdx.x;   // i < 15872 = 512*31
    int f = i / 31, k = i % 31;
    float q = fminf(fmaxf(rintf(dw[i] / s), -128.0f), 127.0f);
    dwqT[k * 512 + f] = q;
  }
}

// LN core on decoded fq0 values; MUST be identical arithmetic in both LN passes.
__device__ __forceinline__ void ln_core(float* a, const f32x4& sc0, const f32x4& sc1,
                                        const f32x4& bi0, const f32x4& bi1) {
  float s = a[0] + a[1] + a[2] + a[3] + a[4] + a[5] + a[6] + a[7];
  float mean = wave_sum(s) / 512.0f;
#pragma unroll
  for (int j = 0; j < 8; ++j) a[j] -= mean;
  float l1 = fabsf(a[0]) + fabsf(a[1]) + fabsf(a[2]) + fabsf(a[3])
           + fabsf(a[4]) + fabsf(a[5]) + fabsf(a[6]) + fabsf(a[7]);
  float denom = wave_sum(l1) / 512.0f + 1e-5f;
#pragma unroll
  for (int j = 0; j < 4; ++j) {
    a[j]     = fmaf(a[j] / denom,     sc0[j], bi0[j]);
    a[4 + j] = fmaf(a[4 + j] / denom, sc1[j], bi1[j]);
  }
}

// pass 1: quantize x -> int8 codes (cache), LN min/max (no t1 store)
__global__ __launch_bounds__(256) void k_lnmm(const float* __restrict__ x, const float* __restrict__ lns,
    const float* __restrict__ lnb, signed char* __restrict__ qx, unsigned* __restrict__ slots) {
  FQ p0 = fq_params(dec(slots[S_XMN]), dec(slots[S_XMX]));
  int lane = threadIdx.x & 63, wv = threadIdx.x >> 6;
  long gw = (long)blockIdx.x * 4 + wv;
  f32x4 sc0 = *(const f32x4*)(lns + lane * 4);
  f32x4 sc1 = *(const f32x4*)(lns + 256 + lane * 4);
  f32x4 bi0 = *(const f32x4*)(lnb + lane * 4);
  f32x4 bi1 = *(const f32x4*)(lnb + 256 + lane * 4);
  float lmn = INF, lmx = -INF;
  for (int r = 0; r < 4; ++r) {
    long row = gw + (long)r * 8192;
    f32x4 v0 = *(const f32x4*)(x + row * 512 + lane * 4);
    f32x4 v1 = *(const f32x4*)(x + row * 512 + 256 + lane * 4);
    float a[8];
    c8x4 c0, c1;
#pragma unroll
    for (int j = 0; j < 4; ++j) {
      int q0 = qcode(v0[j], p0), q1 = qcode(v1[j], p0);
      c0[j] = (signed char)q0; c1[j] = (signed char)q1;
      a[j]     = ((float)q0 - p0.zp) * p0.s;
      a[4 + j] = ((float)q1 - p0.zp) * p0.s;
    }
    *(c8x4*)(qx + row * 512 + lane * 4) = c0;
    *(c8x4*)(qx + row * 512 + 256 + lane * 4) = c1;
    ln_core(a, sc0, sc1, bi0, bi1);
#pragma unroll
    for (int j = 0; j < 8; ++j) { lmn = fminf(lmn, a[j]); lmx = fmaxf(lmx, a[j]); }
  }
  mm_block_atomic(lmn, lmx, slots + S_T1MN, slots + S_T1MX);
}

// pass 2: recompute LN from codes (bitwise-identical), double-fq via LUT -> bf16 int A1
__global__ __launch_bounds__(256) void k_qa(const signed char* __restrict__ qx, const float* __restrict__ lns,
    const float* __restrict__ lnb, unsigned short* __restrict__ A1, const unsigned* __restrict__ slots) {
  __shared__ unsigned short lut[256];
  FQ p0 = fq_params(dec(slots[S_XMN]), dec(slots[S_XMX]));
  FQ p1, p2; fq_pair(slots, S_T1MN, p1, p2);
  {
    int i = threadIdx.x;
    float y1 = ((float)(i - 128) - p1.zp) * p1.s;
    lut[i] = to_bf16(fq_qmz(y1, p2));
  }
  __syncthreads();
  int lane = threadIdx.x & 63, wv = threadIdx.x >> 6;
  long gw = (long)blockIdx.x * 4 + wv;
  f32x4 sc0 = *(const f32x4*)(lns + lane * 4);
  f32x4 sc1 = *(const f32x4*)(lns + 256 + lane * 4);
  f32x4 bi0 = *(const f32x4*)(lnb + lane * 4);
  f32x4 bi1 = *(const f32x4*)(lnb + 256 + lane * 4);
  for (int r = 0; r < 4; ++r) {
    long row = gw + (long)r * 8192;
    c8x4 c0 = *(const c8x4*)(qx + row * 512 + lane * 4);
    c8x4 c1 = *(const c8x4*)(qx + row * 512 + 256 + lane * 4);
    float a[8];
#pragma unroll
    for (int j = 0; j < 4; ++j) {
      a[j]     = ((float)(int)c0[j] - p0.zp) * p0.s;
      a[4 + j] = ((float)(int)c1[j] - p0.zp) * p0.s;
    }
    ln_core(a, sc0, sc1, bi0, bi1);
    s16x4 q0, q1;
#pragma unroll
    for (int j = 0; j < 4; ++j) {
      q0[j] = (short)lut[qidx(a[j], p1)];
      q1[j] = (short)lut[qidx(a[4 + j], p1)];
    }
    *(s16x4*)(A1 + row * 512 + lane * 4) = q0;
    *(s16x4*)(A1 + row * 512 + 256 + lane * 4) = q1;
  }
}

// bf16-integer MFMA GEMM; XCD-chunked remap; global_load_lds staging with
// pre-swizzled SOURCE column (LDS dest linear).
__global__ __launch_bounds__(256) void k_gemm(const unsigned short* __restrict__ A,
    const unsigned short* __restrict__ Bm, const float* __restrict__ bias,
    float* __restrict__ C, int N, unsigned* __restrict__ slots, int mmIdx, int wIdx, int omIdx) {
  __shared__ __align__(16) unsigned short lA[128 * 64];
  __shared__ __align__(16) unsigned short lB[128 * 64];
  FQ p1, p2; fq_pair(slots, mmIdx, p1, p2);
  float sw = fmaxf(dec(slots[wIdx]) / 127.0f, 1e-8f);
  float sAB = p2.s * sw;
  int tid = threadIdx.x;
  int nbx = gridDim.x;
  int total = nbx * gridDim.y;
  int id = blockIdx.y * nbx + blockIdx.x;
  int chunk = total >> 3;
  int d = (id & 7) * chunk + (id >> 3);
  int m0 = (d / nbx) * 128, n0 = (d % nbx) * 128;
  int lane = tid & 63, w = tid >> 6;
  int wm = (w >> 1) * 64, wn = (w & 1) * 64;
  const f32x4 fz = {0.0f, 0.0f, 0.0f, 0.0f};
  f32x4 acc[4][4];
#pragma unroll
  for (int mi = 0; mi < 4; ++mi)
#pragma unroll
    for (int ni = 0; ni < 4; ++ni) acc[mi][ni] = fz;
  // staging geometry: per wave w, call i covers rows w*32+i*8 .. +8, 16B/lane
  int r8 = lane >> 3;                 // row within 8-row group
  int c8 = (lane & 7) * 8;            // u16 col of this lane's 16B chunk
  int srcc = c8 ^ (r8 * 8);           // pre-swizzled source column
  const unsigned short* Abase[4];
  const unsigned short* Bbase[4];
#pragma unroll
  for (int i = 0; i < 4; ++i) {
    int row = w * 32 + i * 8 + r8;
    Abase[i] = A + (long)(m0 + row) * 512 + srcc;
    Bbase[i] = Bm + (long)(n0 + row) * 512 + srcc;
  }
  char* lAc = (char*)lA;
  char* lBc = (char*)lB;
  int fr = lane & 15;
  int fc = (lane >> 4) * 8;
  for (int kt = 0; kt < 8; ++kt) {
    if (kt) __syncthreads();          // previous compute done before overwrite
#pragma unroll
    for (int i = 0; i < 4; ++i) {
      gload_lds16(Abase[i] + kt * 64, lAc + (w * 4 + i) * 1024);
      gload_lds16(Bbase[i] + kt * 64, lBc + (w * 4 + i) * 1024);
    }
    __syncthreads();                  // drains vmcnt -> LDS tile ready
#pragma unroll
    for (int ks = 0; ks < 2; ++ks) {
      s16x8 af[4], bfv[4];
#pragma unroll
      for (int mi = 0; mi < 4; ++mi) {
        int r = wm + mi * 16 + fr;
        af[mi] = *(const s16x8*)&lA[r * 64 + ((ks * 32 + fc) ^ ((r & 7) * 8))];
      }
#pragma unroll
      for (int ni = 0; ni < 4; ++ni) {
        int r = wn + ni * 16 + fr;
        bfv[ni] = *(const s16x8*)&lB[r * 64 + ((ks * 32 + fc) ^ ((r & 7) * 8))];
      }
#pragma unroll
      for (int mi = 0; mi < 4; ++mi)
#pragma unroll
        for (int ni = 0; ni < 4; ++ni)
          acc[mi][ni] = __builtin_amdgcn_mfma_f32_16x16x32_bf16(af[mi], bfv[ni], acc[mi][ni], 0, 0, 0);
    }
  }
  float lmn = INF, lmx = -INF;
  int rb0 = m0 + wm + ((lane >> 4) << 2);
  int cb0 = n0 + wn + (lane & 15);
#pragma unroll
  for (int mi = 0; mi < 4; ++mi) {
#pragma unroll
    for (int ni = 0; ni < 4; ++ni) {
      int col = cb0 + ni * 16;
      float bv = bias[col];
#pragma unroll
      for (int r = 0; r < 4; ++r) {
        int rowi = rb0 + mi * 16 + r;
        float v = sAB * acc[mi][ni][r] + bv;
        C[(long)rowi * N + col] = v;
        lmn = fminf(lmn, v); lmx = fmaxf(lmx, v);
      }
    }
  }
  mm_block_atomic(lmn, lmx, slots + omIdx, slots + omIdx + 1);
}

// GLU: read t4, emit packed (qa,qg); mm(t7) via LUT product (no expf in loop)
__global__ __launch_bounds__(256) void k_glu(const float* __restrict__ t4, unsigned short* __restrict__ pair,
                                             unsigned* __restrict__ slots) {
  __shared__ float lutf[256];
  __shared__ float sglut[256];
  FQ p1, p2; fq_pair(slots, S_T4MN, p1, p2);
  {
    int i = threadIdx.x;
    float y2 = fq_apply(((float)(i - 128) - p1.zp) * p1.s, p2);
    lutf[i] = y2;
    sglut[i] = 1.0f / (1.0f + expf(-y2));
  }
  __syncthreads();
  long i = ((long)blockIdx.x * 256 + threadIdx.x) * 4;
  const long stride = (long)2048 * 256 * 4;
  float lmn = INF, lmx = -INF;
  for (; i < NTOT; i += stride) {
    long r = i >> 9;
    int c = (int)(i & 511);
    const float* pa = t4 + r * 1024 + c;
    f32x4 av = *(const f32x4*)pa;
    f32x4 gv = *(const f32x4*)(pa + 512);
    s16x4 o;
#pragma unroll
    for (int j = 0; j < 4; ++j) {
      int qa = qidx(av[j], p1);
      int qg = qidx(gv[j], p1);
      o[j] = (short)(unsigned short)(qa | (qg << 8));
      float y = lutf[qa] * sglut[qg];
      lmn = fminf(lmn, y); lmx = fmaxf(lmx, y);
    }
    *(s16x4*)(pair + i) = o;
  }
  mm_block_atomic(lmn, lmx, slots + S_T7MN, slots + S_T7MX);
}

// decode pair -> t7 value (identical product) -> double-fq composed int8 code q7
__global__ __launch_bounds__(256) void k_qt7(const unsigned short* __restrict__ pair,
                                             signed char* __restrict__ q7,
                                             const unsigned* __restrict__ slots) {
  __shared__ float lutf[256];
  __shared__ float sglut[256];
  __shared__ signed char lutq[256];
  FQ g1, g2; fq_pair(slots, S_T4MN, g1, g2);
  FQ p1, p2; fq_pair(slots, S_T7MN, p1, p2);
  {
    int i = threadIdx.x;
    float y2 = fq_apply(((float)(i - 128) - g1.zp) * g1.s, g2);
    lutf[i] = y2;
    sglut[i] = 1.0f / (1.0f + expf(-y2));
    float y1 = ((float)(i - 128) - p1.zp) * p1.s;
    float q = fminf(fmaxf(rintf(y1 / p2.s) + p2.zp, -128.0f), 127.0f);
    lutq[i] = (signed char)(int)q;
  }
  __syncthreads();
  long i = ((long)blockIdx.x * 256 + threadIdx.x) * 4;
  const long stride = (long)2048 * 256 * 4;
  for (; i < NTOT; i += stride) {
    s16x4 pv = *(const s16x4*)(pair + i);
    c8x4 o;
#pragma unroll
    for (int j = 0; j < 4; ++j) {
      unsigned u = (unsigned short)pv[j];
      float y = lutf[u & 255] * sglut[u >> 8];
      o[j] = lutq[qidx(y, p1)];
    }
    *(c8x4*)(q7 + i) = o;
  }
}

// depthwise conv, LDS-tiled: block = (t-tile 32, f-tile 64, b). Window stored
// TRANSPOSED in LDS as f32 (code - zp2; pads = 0.0f), stride 65 (bank-conflict
// free). Lane owns f, wave owns 8 t's. k- and j-loops constant-trip; window is
// LDS (dynamically indexable) so nothing demotes to scratch. Exact integer
// sums; identical template both passes.
template<int STORE>
__global__ __launch_bounds__(256) void k_conv(const signed char* __restrict__ q7,
    const float* __restrict__ dwqT, const float* __restrict__ dwb,
    signed char* __restrict__ qcv, const float* __restrict__ gs, const float* __restrict__ mu,
    const float* __restrict__ bt, unsigned* __restrict__ slots) {
  __shared__ float win[64][65];       // [f_local][t_local], stride 65 -> conflict-free
  __shared__ signed char lutq[256];
  FQ p1, p2; fq_pair(slots, S_T7MN, p1, p2);
  float sdw = fmaxf(dec(slots[S_DW]) / 127.0f, 1e-8f);
  float scv = p2.s * sdw;
  float zp2 = p2.zp;
  FQ c1, c2;
  if (STORE) {
    fq_pair(slots, S_CVMN, c1, c2);
    int i = threadIdx.x;
    float y1 = ((float)(i - 128) - c1.zp) * c1.s;
    float q = fminf(fmaxf(rintf(y1 / c2.s) + c2.zp, -128.0f), 127.0f);
    lutq[i] = (signed char)(int)q;
  }
  int tid = threadIdx.x;
  int t0 = blockIdx.x * 32;
  int f0 = blockIdx.y * 64;
  int b = blockIdx.z;
  // ---- load phase: rows r=0..61 (t = t0-15+r), thread (r = tid>>2, 16 f's) ----
  {
    int r = tid >> 2;
    int fj = (tid & 3) * 16;
    if (r < 62) {
      int t = t0 - 15 + r;
      if ((unsigned)t < 1024u) {
        i32x4 v4 = *(const i32x4*)(q7 + ((long)b * 1024 + t) * 512 + f0 + fj);
#pragma unroll
        for (int wo = 0; wo < 4; ++wo) {
          int word = v4[wo];
#pragma unroll
          for (int bb = 0; bb < 4; ++bb) {
            int code = (int)(signed char)((word >> (8 * bb)) & 255);
            win[fj + wo * 4 + bb][r] = (float)code - zp2;
          }
        }
      } else {
#pragma unroll
        for (int u = 0; u < 16; ++u) win[fj + u][r] = 0.0f;
      }
    }
  }
  __syncthreads();
  // ---- compute phase: lane = f, wave = 8 t's ----
  int lane = tid & 63, w = tid >> 6;
  int f = f0 + lane;
  float wv[31];
#pragma unroll
  for (int k = 0; k < 31; ++k) wv[k] = dwqT[k * 512 + f];
  const float* wrow = &win[lane][w * 8];
  float o[8];
#pragma unroll
  for (int j = 0; j < 8; ++j) o[j] = 0.0f;
#pragma unroll
  for (int k = 0; k < 31; ++k) {
    float wk = wv[k];
#pragma unroll
    for (int j = 0; j < 8; ++j)
      o[j] += wrow[j + k] * wk;       // exact integers; k ascending per output
  }
  float bias = dwb[f];
  float gsv = 0.f, muv = 0.f, btv = 0.f;
  if (STORE) { gsv = gs[f]; muv = mu[f]; btv = bt[f]; }
  signed char* orow = STORE ? (qcv + ((long)b * 1024 + t0 + w * 8) * 512 + f) : nullptr;
  float lmn = INF, lmx = -INF;
#pragma unroll
  for (int j = 0; j < 8; ++j) {
    float v = fmaf(scv, o[j], bias);
    if (STORE) {
      signed char qc = lutq[qidx(v, c1)];
      orow[(long)j * 512] = qc;
      float y2 = ((float)(int)qc - c2.zp) * c2.s;
      float z = fmaf(y2 - muv, gsv, btv);
      lmn = fminf(lmn, z); lmx = fmaxf(lmx, z);
    } else {
      lmn = fminf(lmn, v); lmx = fmaxf(lmx, v);
    }
  }
  if (STORE) mm_block_atomic(lmn, lmx, slots + S_BNMN, slots + S_BNMX);
  else       mm_block_atomic(lmn, lmx, slots + S_CVMN, slots + S_CVMX);
}

// silu min/max: qcv codes -> bn -> fq2-index -> sillut (no expf in loop)
__global__ __launch_bounds__(256) void k_silumm(const signed char* __restrict__ qcv,
    const float* __restrict__ gs, const float* __restrict__ mu, const float* __restrict__ bt,
    unsigned* __restrict__ slots) {
  __shared__ float sillut[256];
  FQ c1, c2; fq_pair(slots, S_CVMN, c1, c2);
  FQ b1q, b2q; fq_pair(slots, S_BNMN, b1q, b2q);
  {
    int i = threadIdx.x;
    float z2 = fq_apply(((float)(i - 128) - b1q.zp) * b1q.s, b2q);
    sillut[i] = z2 * (1.0f / (1.0f + expf(-z2)));
  }
  __syncthreads();
  float s2 = c2.s, zp2 = c2.zp;
  long i = ((long)blockIdx.x * 256 + threadIdx.x) * 4;
  const long stride = (long)2048 * 256 * 4;
  float lmn = INF, lmx = -INF;
  for (; i < NTOT; i += stride) {
    int f0 = (int)(i & 511);
    c8x4 qv = *(const c8x4*)(qcv + i);
    f32x4 g4 = *(const f32x4*)(gs + f0);
    f32x4 m4 = *(const f32x4*)(mu + f0);
    f32x4 b4 = *(const f32x4*)(bt + f0);
#pragma unroll
    for (int j = 0; j < 4; ++j) {
      float y2 = ((float)(int)qv[j] - zp2) * s2;
      float z = fmaf(y2 - m4[j], g4[j], b4[j]);
      float si = sillut[qidx(z, b1q)];
      lmn = fminf(lmn, si); lmx = fmaxf(lmx, si);
    }
  }
  mm_block_atomic(lmn, lmx, slots + S_SIMN, slots + S_SIMX);
}

// A2 build: qcv code -> bn -> composed LUT (fq2 -> silu -> double-fq -> bf16 int)
__global__ __launch_bounds__(256) void k_q2(const signed char* __restrict__ qcv,
    const float* __restrict__ gs, const float* __restrict__ mu, const float* __restrict__ bt,
    unsigned short* __restrict__ A2, const unsigned* __restrict__ slots) {
  __shared__ unsigned short lutc[256];
  FQ c1, c2; fq_pair(slots, S_CVMN, c1, c2);
  FQ b1q, b2q; fq_pair(slots, S_BNMN, b1q, b2q);
  FQ s1q, s2q; fq_pair(slots, S_SIMN, s1q, s2q);
  {
    int i = threadIdx.x;
    float z2 = fq_apply(((float)(i - 128) - b1q.zp) * b1q.s, b2q);
    float si = z2 * (1.0f / (1.0f + expf(-z2)));
    float ys = ((float)(qidx(si, s1q) - 128) - s1q.zp) * s1q.s;
    lutc[i] = to_bf16(fq_qmz(ys, s2q));
  }
  __syncthreads();
  float s2 = c2.s, zp2 = c2.zp;
  long i = ((long)blockIdx.x * 256 + threadIdx.x) * 4;
  const long stride = (long)2048 * 256 * 4;
  for (; i < NTOT; i += stride) {
    int f0 = (int)(i & 511);
    c8x4 qv = *(const c8x4*)(qcv + i);
    f32x4 g4 = *(const f32x4*)(gs + f0);
    f32x4 m4 = *(const f32x4*)(mu + f0);
    f32x4 b4 = *(const f32x4*)(bt + f0);
    s16x4 o;
#pragma unroll
    for (int j = 0; j < 4; ++j) {
      float y2 = ((float)(int)qv[j] - zp2) * s2;
      float z = fmaf(y2 - m4[j], g4[j], b4[j]);
      o[j] = (short)lutc[qidx(z, b1q)];
    }
    *(s16x4*)(A2 + i) = o;
  }
}

__global__ __launch_bounds__(256) void k_final(const float* __restrict__ t18, float* __restrict__ out,
                                               const unsigned* __restrict__ slots) {
  FQ p = fq_params(dec(slots[S_T18MN]), dec(slots[S_T18MX]));
  long i = ((long)blockIdx.x * 256 + threadIdx.x) * 4;
  const long stride = (long)2048 * 256 * 4;
  for (; i < NTOT; i += stride) {
    f32x4 v = *(const f32x4*)(t18 + i);
    f32x4 o;
#pragma unroll
    for (int j = 0; j < 4; ++j) o[j] = fq_apply(v[j], p);
    *(f32x4*)(out + i) = o;
  }
}

extern "C" void kernel_launch(void* const* d_in, const int* in_sizes, int n_in,
                              void* d_out, int out_size, void* d_ws, size_t ws_size,
                              hipStream_t stream) {
  const float* x   = (const float*)d_in[0];
  const float* lns = (const float*)d_in[1];
  const float* lnb = (const float*)d_in[2];
  const float* w1  = (const float*)d_in[3];
  const float* b1  = (const float*)d_in[4];
  const float* dw  = (const float*)d_in[5];
  const float* dwb = (const float*)d_in[6];
  const float* gm  = (const float*)d_in[7];
  const float* bt  = (const float*)d_in[8];
  const float* mu  = (const float*)d_in[9];
  const float* vr  = (const float*)d_in[10];
  const float* w2  = (const float*)d_in[11];
  const float* b2  = (const float*)d_in[12];
  float* out = (float*)d_out;
  char* ws = (char*)d_ws;

  // workspace (aliased lifetimes):
  //  [0,134M):        t4; after t4 dead: qcv [0,16.7M), A2 [16.7M,50.3M), t18 [50.3M,117.4M)
  //  [134M,167.8M):   A1 (bf16) -> pair (u16)
  //  [167.8M,184.5M): qx (int8) -> q7 (int8)
  //  [184.5M...):     w1q(1MB), w2q(0.5MB), dwqT(63.5KB), gs(2KB), slots
  const size_t O_A2  = 16777216;
  const size_t O_T18 = 50331648;
  const size_t O_A1  = 134217728;
  const size_t O_QX  = 167772160;
  const size_t O_WQ  = 184549376;
  const size_t NEED = O_WQ + 1048576 + 524288 + 63488 + 2048 + 256;
  if (ws_size < NEED) return;

  float* t4   = (float*)ws;
  signed char* qcv = (signed char*)ws;
  unsigned short* A2 = (unsigned short*)(ws + O_A2);
  float* t18  = (float*)(ws + O_T18);
  unsigned short* A1 = (unsigned short*)(ws + O_A1);
  unsigned short* pair = (unsigned short*)(ws + O_A1);
  signed char* qx = (signed char*)(ws + O_QX);
  signed char* q7 = (signed char*)(ws + O_QX);
  unsigned short* w1q = (unsigned short*)(ws + O_WQ);
  unsigned short* w2q = (unsigned short*)(ws + O_WQ + 1048576);
  float* dwqT = (float*)(ws + O_WQ + 1048576 + 524288);
  float* gs  = (float*)(ws + O_WQ + 1048576 + 524288 + 63488);
  unsigned* slots = (unsigned*)(ws + O_WQ + 1048576 + 524288 + 63488 + 2048);

  k_init<<<1, 512, 0, stream>>>(slots, gm, vr, gs);
  k_wabs<<<3134, 256, 0, stream>>>(w1, w2, dw, slots);
  k_wq<<<3134, 256, 0, stream>>>(w1, w2, dw, w1q, w2q, dwqT, slots);
  k_redmm<<<2048, 256, 0, stream>>>(x, slots);
  k_lnmm<<<2048, 256, 0, stream>>>(x, lns, lnb, qx, slots);
  k_qa<<<2048, 256, 0, stream>>>(qx, lns, lnb, A1, slots);
  k_gemm<<<dim3(8, 256), 256, 0, stream>>>(A1, w1q, b1, t4, 1024, slots, S_T1MN, S_W1, S_T4MN);
  k_glu<<<2048, 256, 0, stream>>>(t4, pair, slots);
  k_qt7<<<2048, 256, 0, stream>>>(pair, q7, slots);
  k_conv<0><<<dim3(32, 8, 32), 256, 0, stream>>>(q7, dwqT, dwb, nullptr, gs, mu, bt, slots);
  k_conv<1><<<dim3(32, 8, 32), 256, 0, stream>>>(q7, dwqT, dwb, qcv, gs, mu, bt, slots);
  k_silumm<<<2048, 256, 0, stream>>>(qcv, gs, mu, bt, slots);
  k_q2<<<2048, 256, 0, stream>>>(qcv, gs, mu, bt, A2, slots);
  k_gemm<<<dim3(4, 256), 256, 0, stream>>>(A2, w2q, b2, t18, 512, slots, S_SIMN, S_W2, S_T18MN);
  k_final<<<2048, 256, 0, stream>>>(t18, out, slots);
}